// Round 1
// baseline (182.321 us; speedup 1.0000x reference)
//
#include <hip/hip_runtime.h>
#include <hip/hip_bf16.h>

#define HIDDEN 2048
#define BM 128
#define BN 128
#define BK 32
#define LDSL 40   // padded LDS row stride in bf16 elems (80 B, 16B-aligned, conflict-free-ish)

typedef __attribute__((ext_vector_type(8))) short bf16x8;
typedef __attribute__((ext_vector_type(4))) float f32x4;
typedef __attribute__((ext_vector_type(4))) unsigned short u16x4;

// ---- Build dense W (f32) from COO with duplicate summing ----
__global__ void build_w_kernel(const float* __restrict__ vals,
                               const int* __restrict__ rows,
                               const int* __restrict__ cols,
                               float* __restrict__ W, int nnz) {
    int k = blockIdx.x * blockDim.x + threadIdx.x;
    if (k < nnz) {
        atomicAdd(&W[(size_t)rows[k] * HIDDEN + cols[k]], vals[k]);
    }
}

// ---- out[m,n] = xc[m,n] + alpha * sum_k xp[m,k] * W[n,k] ----
// A = xp (MxK row-major), "B^T" = W (NxK row-major) -> both K-contiguous.
__global__ __launch_bounds__(256) void gemm_kernel(
    const float* __restrict__ xc,
    const float* __restrict__ xp,
    const float* __restrict__ W,
    const float* __restrict__ alpha_p,
    float* __restrict__ out)
{
    __shared__ unsigned short As[BM * LDSL];
    __shared__ unsigned short Bs[BN * LDSL];

    const int tid  = threadIdx.x;
    const int lane = tid & 63;
    const int wave = tid >> 6;
    const int l15  = lane & 15;
    const int l4   = lane >> 4;

    const int m0 = blockIdx.x * BM;
    const int n0 = blockIdx.y * BN;
    // 2x2 wave grid; each wave owns a 64x64 output sub-tile
    const int wm = (wave >> 1) * 64;
    const int wn = (wave & 1) * 64;

    f32x4 acc[4][4] = {};   // [mi][ni], 16x16 fragments

    for (int k0 = 0; k0 < HIDDEN; k0 += BK) {
        // ---- stage A (xp) and B (W rows) tiles: f32 global -> bf16(trunc) LDS ----
        // 128 rows x 32 cols = 1024 float4 loads per matrix; 4 per thread.
        #pragma unroll
        for (int q = 0; q < 4; ++q) {
            const int f   = tid + 256 * q;   // 0..1023
            const int row = f >> 3;          // 0..127
            const int c4  = f & 7;           // float4 index within the 32-wide row
            f32x4 a = *(const f32x4*)(xp + (size_t)(m0 + row) * HIDDEN + k0 + c4 * 4);
            f32x4 b = *(const f32x4*)(W  + (size_t)(n0 + row) * HIDDEN + k0 + c4 * 4);
            u16x4 ah, bh;
            #pragma unroll
            for (int j = 0; j < 4; ++j) {
                ah[j] = (unsigned short)(__float_as_uint(a[j]) >> 16);
                bh[j] = (unsigned short)(__float_as_uint(b[j]) >> 16);
            }
            *(u16x4*)(&As[row * LDSL + c4 * 4]) = ah;
            *(u16x4*)(&Bs[row * LDSL + c4 * 4]) = bh;
        }
        __syncthreads();

        // ---- LDS -> fragments -> MFMA ----
        // A frag: lane holds A[l15][8*l4 + j]; B frag: lane holds B[8*l4 + j][l15] = W[n=l15][k...]
        bf16x8 afrag[4], bfrag[4];
        #pragma unroll
        for (int i = 0; i < 4; ++i) {
            afrag[i] = *(const bf16x8*)(&As[(wm + i * 16 + l15) * LDSL + l4 * 8]);
            bfrag[i] = *(const bf16x8*)(&Bs[(wn + i * 16 + l15) * LDSL + l4 * 8]);
        }
        #pragma unroll
        for (int mi = 0; mi < 4; ++mi)
            #pragma unroll
            for (int ni = 0; ni < 4; ++ni)
                acc[mi][ni] = __builtin_amdgcn_mfma_f32_16x16x32_bf16(
                    afrag[mi], bfrag[ni], acc[mi][ni], 0, 0, 0);
        __syncthreads();
    }

    // ---- epilogue: out = xc + alpha * acc ----
    // C/D mapping (verified m89): col = lane&15, row = (lane>>4)*4 + reg
    const float alpha = alpha_p[0];
    #pragma unroll
    for (int mi = 0; mi < 4; ++mi) {
        #pragma unroll
        for (int r = 0; r < 4; ++r) {
            const int m = m0 + wm + mi * 16 + l4 * 4 + r;
            #pragma unroll
            for (int ni = 0; ni < 4; ++ni) {
                const int n = n0 + wn + ni * 16 + l15;
                const size_t o = (size_t)m * HIDDEN + n;
                out[o] = xc[o] + alpha * acc[mi][ni][r];
            }
        }
    }
}

extern "C" void kernel_launch(void* const* d_in, const int* in_sizes, int n_in,
                              void* d_out, int out_size, void* d_ws, size_t ws_size,
                              hipStream_t stream) {
    const float* xc    = (const float*)d_in[0];   // x_current [4,2048,2048]
    const float* xp    = (const float*)d_in[1];   // x_prev    [4,2048,2048]
    const float* alpha = (const float*)d_in[2];   // scalar
    const float* vals  = (const float*)d_in[3];   // [NNZ]
    const int*   idx   = (const int*)d_in[4];     // [2, NNZ] flat
    float* out = (float*)d_out;
    float* W   = (float*)d_ws;                    // 2048*2048 f32 = 16 MB

    const int nnz = in_sizes[3];
    const int M   = in_sizes[0] / HIDDEN;         // 8192

    hipMemsetAsync(W, 0, (size_t)HIDDEN * HIDDEN * sizeof(float), stream);
    build_w_kernel<<<(nnz + 255) / 256, 256, 0, stream>>>(vals, idx, idx + nnz, W, nnz);

    dim3 grid(M / BM, HIDDEN / BN);               // 64 x 16
    gemm_kernel<<<grid, 256, 0, stream>>>(xc, xp, W, alpha, out);
}

// Round 2
// 155.226 us; speedup vs baseline: 1.1745x; 1.1745x over previous
//
#include <hip/hip_runtime.h>
#include <hip/hip_bf16.h>

#define HIDDEN 2048
#define BM 128
#define BN 128
#define BK 32

typedef __attribute__((ext_vector_type(8))) short bf16x8;
typedef __attribute__((ext_vector_type(4))) float f32x4;
typedef __attribute__((ext_vector_type(8))) unsigned short u16x8;

// HBM -> LDS direct, 16B per lane. LDS dest is wave-uniform base + lane*16.
#define GLDS(gptr, lptr)                                                        \
    __builtin_amdgcn_global_load_lds(                                          \
        (const __attribute__((address_space(1))) void*)(gptr),                 \
        (__attribute__((address_space(3))) void*)(lptr), 16, 0, 0)

// ---- Build dense W (f32) from COO with duplicate summing ----
__global__ void build_w_kernel(const float* __restrict__ vals,
                               const int* __restrict__ rows,
                               const int* __restrict__ cols,
                               float* __restrict__ W, int nnz) {
    int k = blockIdx.x * blockDim.x + threadIdx.x;
    if (k < nnz) atomicAdd(&W[(size_t)rows[k] * HIDDEN + cols[k]], vals[k]);
}

// ---- f32 -> bf16(trunc), 8 elems/thread, grid-stride ----
__global__ void convert_kernel(const float* __restrict__ src,
                               unsigned short* __restrict__ dst, int n8) {
    int i = blockIdx.x * blockDim.x + threadIdx.x;
    const int stride = gridDim.x * blockDim.x;
    for (; i < n8; i += stride) {
        f32x4 a = ((const f32x4*)src)[2 * i];
        f32x4 b = ((const f32x4*)src)[2 * i + 1];
        u16x8 h;
        #pragma unroll
        for (int j = 0; j < 4; ++j) {
            h[j]     = (unsigned short)(__float_as_uint(a[j]) >> 16);
            h[4 + j] = (unsigned short)(__float_as_uint(b[j]) >> 16);
        }
        ((u16x8*)dst)[i] = h;
    }
}

// ---- out[m,n] = xc[m,n] + alpha * sum_k xp[m,k] * W[n,k] (m97 structure) ----
__global__ __launch_bounds__(256) void gemm_kernel(
    const float* __restrict__ xc,
    const unsigned short* __restrict__ xpb,   // bf16 [8192][2048]
    const unsigned short* __restrict__ Wb,    // bf16 [2048][2048]
    const float* __restrict__ alpha_p,
    float* __restrict__ out)
{
    __shared__ unsigned short As[BM * BK];   // 8 KB, linear [128][32]
    __shared__ unsigned short Bs[BN * BK];   // 8 KB

    const int tid  = threadIdx.x;
    const int lane = tid & 63;
    const int wave = tid >> 6;
    const int l15  = lane & 15;
    const int l4   = lane >> 4;

    const int m0 = blockIdx.x * BM;
    const int n0 = blockIdx.y * BN;
    const int wm = (wave >> 1) * 64;
    const int wn = (wave & 1) * 64;

    // Staging geometry: tile = 512 chunks of 16B; chunk c -> row=c>>2, col=(c&3)*8.
    // Wave w issue q covers chunks [q*256 + w*64, +64); LDS elem base (q*4+w)*512.
    const int c0 = wave * 64 + lane;          // q=0 chunk for this lane
    const int c1 = c0 + 256;                  // q=1 chunk
    const unsigned short* aA0 = xpb + (size_t)(m0 + (c0 >> 2)) * HIDDEN + (c0 & 3) * 8;
    const unsigned short* aA1 = xpb + (size_t)(m0 + (c1 >> 2)) * HIDDEN + (c1 & 3) * 8;
    const unsigned short* aB0 = Wb  + (size_t)(n0 + (c0 >> 2)) * HIDDEN + (c0 & 3) * 8;
    const unsigned short* aB1 = Wb  + (size_t)(n0 + (c1 >> 2)) * HIDDEN + (c1 & 3) * 8;

    unsigned short* ldsA0 = As + wave * 512;
    unsigned short* ldsA1 = As + (4 + wave) * 512;
    unsigned short* ldsB0 = Bs + wave * 512;
    unsigned short* ldsB1 = Bs + (4 + wave) * 512;

    f32x4 acc[4][4] = {};   // [mi][ni] 16x16x32 fragments

    for (int k0 = 0; k0 < HIDDEN; k0 += BK) {
        GLDS(aA0, ldsA0);
        GLDS(aA1, ldsA1);
        GLDS(aB0, ldsB0);
        GLDS(aB1, ldsB1);
        __syncthreads();   // drains vmcnt(0) -> LDS tiles ready

        bf16x8 af[4], bfr[4];
        #pragma unroll
        for (int i = 0; i < 4; ++i) {
            af[i]  = *(const bf16x8*)(&As[(wm + i * 16 + l15) * BK + l4 * 8]);
            bfr[i] = *(const bf16x8*)(&Bs[(wn + i * 16 + l15) * BK + l4 * 8]);
        }
        #pragma unroll
        for (int mi = 0; mi < 4; ++mi)
            #pragma unroll
            for (int ni = 0; ni < 4; ++ni)
                acc[mi][ni] = __builtin_amdgcn_mfma_f32_16x16x32_bf16(
                    af[mi], bfr[ni], acc[mi][ni], 0, 0, 0);
        __syncthreads();   // all reads done before next staging overwrites

        aA0 += BK; aA1 += BK; aB0 += BK; aB1 += BK;
    }

    // epilogue: C/D map col=lane&15, row=(lane>>4)*4+reg  (verified round 0)
    const float alpha = alpha_p[0];
    #pragma unroll
    for (int mi = 0; mi < 4; ++mi) {
        #pragma unroll
        for (int r = 0; r < 4; ++r) {
            const int m = m0 + wm + mi * 16 + l4 * 4 + r;
            #pragma unroll
            for (int ni = 0; ni < 4; ++ni) {
                const int n = n0 + wn + ni * 16 + l15;
                const size_t o = (size_t)m * HIDDEN + n;
                out[o] = xc[o] + alpha * acc[mi][ni][r];
            }
        }
    }
}

extern "C" void kernel_launch(void* const* d_in, const int* in_sizes, int n_in,
                              void* d_out, int out_size, void* d_ws, size_t ws_size,
                              hipStream_t stream) {
    const float* xc    = (const float*)d_in[0];
    const float* xp    = (const float*)d_in[1];
    const float* alpha = (const float*)d_in[2];
    const float* vals  = (const float*)d_in[3];
    const int*   idx   = (const int*)d_in[4];
    float* out = (float*)d_out;

    float*          W   = (float*)d_ws;                                   // 16 MB
    unsigned short* Wb  = (unsigned short*)((char*)d_ws + (16 << 20));    //  8 MB
    unsigned short* xpb = (unsigned short*)((char*)d_ws + (24 << 20));    // 32 MB

    const int nnz = in_sizes[3];
    const int M   = in_sizes[0] / HIDDEN;   // 8192

    hipMemsetAsync(W, 0, (size_t)HIDDEN * HIDDEN * sizeof(float), stream);
    build_w_kernel<<<(nnz + 255) / 256, 256, 0, stream>>>(vals, idx, idx + nnz, W, nnz);

    // one-time bf16 conversions (xp independent of W; same stream order is fine)
    convert_kernel<<<2048, 256, 0, stream>>>(xp, xpb, (in_sizes[1]) / 8);
    convert_kernel<<<2048, 256, 0, stream>>>(W, Wb, (HIDDEN * HIDDEN) / 8);

    dim3 grid(M / BM, HIDDEN / BN);   // 64 x 16
    gemm_kernel<<<grid, 256, 0, stream>>>(xc, xpb, Wb, alpha, out);
}

// Round 3
// 131.709 us; speedup vs baseline: 1.3843x; 1.1786x over previous
//
#include <hip/hip_runtime.h>
#include <hip/hip_bf16.h>

#define HIDDEN 2048
#define NT 32          // K tiles of 64
#define BK 64
#define LDS_BYTES 132096  // 2x32KB A + 2x32KB B + 1KB dummy sink

typedef __attribute__((ext_vector_type(8))) short bf16x8;
typedef __attribute__((ext_vector_type(4))) float f32x4;
typedef __attribute__((ext_vector_type(8))) unsigned short u16x8;

#define GLDS(gptr, lptr)                                                       \
    __builtin_amdgcn_global_load_lds(                                          \
        (const __attribute__((address_space(1))) void*)(gptr),                 \
        (__attribute__((address_space(3))) void*)(lptr), 16, 0, 0)

#define SCHED0() __builtin_amdgcn_sched_barrier(0)
#define BARRIER() __builtin_amdgcn_s_barrier()
#define LGKM0() do { asm volatile("s_waitcnt lgkmcnt(0)" ::: "memory"); SCHED0(); } while (0)
#define VMCNT(n) asm volatile("s_waitcnt vmcnt(" #n ")" ::: "memory")

// ---- Build dense W (f32) from COO with duplicate summing ----
__global__ void build_w_kernel(const float* __restrict__ vals,
                               const int* __restrict__ rows,
                               const int* __restrict__ cols,
                               float* __restrict__ W, int nnz) {
    int k = blockIdx.x * blockDim.x + threadIdx.x;
    if (k < nnz) atomicAdd(&W[(size_t)rows[k] * HIDDEN + cols[k]], vals[k]);
}

// ---- f32 -> bf16(trunc), 8 elems/thread, grid-stride ----
__global__ void convert_kernel(const float* __restrict__ src,
                               unsigned short* __restrict__ dst, int n8) {
    int i = blockIdx.x * blockDim.x + threadIdx.x;
    const int stride = gridDim.x * blockDim.x;
    for (; i < n8; i += stride) {
        f32x4 a = ((const f32x4*)src)[2 * i];
        f32x4 b = ((const f32x4*)src)[2 * i + 1];
        u16x8 h;
        #pragma unroll
        for (int j = 0; j < 4; ++j) {
            h[j]     = (unsigned short)(__float_as_uint(a[j]) >> 16);
            h[4 + j] = (unsigned short)(__float_as_uint(b[j]) >> 16);
        }
        ((u16x8*)dst)[i] = h;
    }
}

// ---- 256x256x64 8-wave 8-phase GEMM: out = xc + alpha * (xp @ W^T) ----
__global__ __launch_bounds__(512, 2) void gemm_kernel(
    const float* __restrict__ xc,
    const unsigned short* __restrict__ xpb,   // bf16 [8192][2048]
    const unsigned short* __restrict__ Wb,    // bf16 [2048][2048]
    const float* __restrict__ alpha_p,
    float* __restrict__ out)
{
    extern __shared__ __align__(16) char lds[];
    char* const ldsA = lds;             // [2 bufs][2 halves 16KB] = 64KB
    char* const ldsB = lds + 65536;     // 64KB
    char* const ldsX = lds + 131072;    // 1KB dummy sink for tail staging

    const int tid  = threadIdx.x;
    const int lane = tid & 63;
    const int wave = tid >> 6;
    const int l15  = lane & 15;
    const int l4   = lane >> 4;

    const int m0 = (blockIdx.x >> 3) * 256;
    const int n0 = (blockIdx.x & 7) * 256;
    const int wm = (wave >> 2) * 128;   // 2 M-waves
    const int wn = (wave & 3) * 64;     // 4 N-waves

    // ---- staging: per half-tile (128 rows x 64 cols bf16 = 1024 16B chunks),
    // chunk = wave*128 + q*64 + lane; row = wave*16 + q*8 + (lane>>3); slot = lane&7.
    // T2 swizzle: LDS dest stays linear, global SOURCE slot is XOR'd with row&7.
    const int srow  = lane >> 3;
    const int sslot = (lane & 7) ^ srow;
    const unsigned short* const gA0 = xpb + (size_t)(m0 + wave * 16 + 0 + srow) * HIDDEN + sslot * 8;
    const unsigned short* const gA1 = xpb + (size_t)(m0 + wave * 16 + 8 + srow) * HIDDEN + sslot * 8;
    const unsigned short* const gB0 = Wb  + (size_t)(n0 + wave * 16 + 0 + srow) * HIDDEN + sslot * 8;
    const unsigned short* const gB1 = Wb  + (size_t)(n0 + wave * 16 + 8 + srow) * HIDDEN + sslot * 8;

#define STAGE(G0, G1, LBASE, t, h)                                             \
    do {                                                                       \
        const int _t = (t);                                                    \
        if (_t < NT) {                                                         \
            const size_t _o = (size_t)_t * BK + (size_t)(h) * (128 * HIDDEN);  \
            char* const _d = (LBASE) + (_t & 1) * 32768 + (h) * 16384 + wave * 2048; \
            GLDS((G0) + _o, _d);                                               \
            GLDS((G1) + _o, _d + 1024);                                        \
        } else {                                                               \
            GLDS(gA0, ldsX);                                                   \
            GLDS(gA1, ldsX);                                                   \
        }                                                                      \
    } while (0)

    // ---- ds_read addressing (swizzled to match staging) ----
    // frag (r, kk): byte = (r&127)*128 + (((kk*4 + l4) ^ (l15&7)) * 16), r&7 == l15&7
    const int swz  = l15 & 7;
    const int sk0  = ((l4 + 0) ^ swz) * 16;
    const int sk1  = ((l4 + 4) ^ swz) * 16;
    const int rowb = l15 * 128;
    const char* const AwaveBase = ldsA + (wm >> 7) * 16384;
    const char* const BwaveBase = ldsB + (wn >> 7) * 16384 + ((wn & 64) << 7);

    f32x4 acc[8][4] = {};   // [mi 0..7][nj 0..3]

    // ---- prologue: tile0 all 4 halves + tile1 A-h0; leave 2 loads in flight ----
    STAGE(gA0, gA1, ldsA, 0, 0);
    STAGE(gA0, gA1, ldsA, 0, 1);
    STAGE(gB0, gB1, ldsB, 0, 0);
    STAGE(gB0, gB1, ldsB, 0, 1);
    STAGE(gA0, gA1, ldsA, 1, 0);
    VMCNT(2);
    SCHED0(); BARRIER(); SCHED0();

    for (int tt = 0; tt < NT; ++tt) {
        const int c = tt & 1;
        const char* const Aw = AwaveBase + c * 32768;
        const char* const Bw = BwaveBase + c * 32768;

        bf16x8 a0[4][2], a1[4][2], b0[2][2], b1[2][2];

        // ======== Phase 1: read a0(8)+b0(4) | stage A(t+1)h1 | MFMA M0N0 ========
        #pragma unroll
        for (int mi = 0; mi < 4; ++mi) {
            a0[mi][0] = *(const bf16x8*)(Aw + mi * 2048 + rowb + sk0);
            a0[mi][1] = *(const bf16x8*)(Aw + mi * 2048 + rowb + sk1);
        }
        #pragma unroll
        for (int nj = 0; nj < 2; ++nj) {
            b0[nj][0] = *(const bf16x8*)(Bw + nj * 2048 + rowb + sk0);
            b0[nj][1] = *(const bf16x8*)(Bw + nj * 2048 + rowb + sk1);
        }
        STAGE(gA0, gA1, ldsA, tt + 1, 1);
        SCHED0(); BARRIER();
        LGKM0();
        __builtin_amdgcn_s_setprio(1);
        #pragma unroll
        for (int mi = 0; mi < 4; ++mi)
            #pragma unroll
            for (int nj = 0; nj < 2; ++nj) {
                acc[mi][nj] = __builtin_amdgcn_mfma_f32_16x16x32_bf16(a0[mi][0], b0[nj][0], acc[mi][nj], 0, 0, 0);
                acc[mi][nj] = __builtin_amdgcn_mfma_f32_16x16x32_bf16(a0[mi][1], b0[nj][1], acc[mi][nj], 0, 0, 0);
            }
        __builtin_amdgcn_s_setprio(0);
        SCHED0(); BARRIER(); SCHED0();

        // ======== Phase 2: read b1(4) | stage B(t+1)h0 | MFMA M0N1 ========
        #pragma unroll
        for (int nj = 0; nj < 2; ++nj) {
            b1[nj][0] = *(const bf16x8*)(Bw + (2 + nj) * 2048 + rowb + sk0);
            b1[nj][1] = *(const bf16x8*)(Bw + (2 + nj) * 2048 + rowb + sk1);
        }
        STAGE(gB0, gB1, ldsB, tt + 1, 0);
        SCHED0(); BARRIER();
        LGKM0();
        __builtin_amdgcn_s_setprio(1);
        #pragma unroll
        for (int mi = 0; mi < 4; ++mi)
            #pragma unroll
            for (int nj = 0; nj < 2; ++nj) {
                acc[mi][2 + nj] = __builtin_amdgcn_mfma_f32_16x16x32_bf16(a0[mi][0], b1[nj][0], acc[mi][2 + nj], 0, 0, 0);
                acc[mi][2 + nj] = __builtin_amdgcn_mfma_f32_16x16x32_bf16(a0[mi][1], b1[nj][1], acc[mi][2 + nj], 0, 0, 0);
            }
        __builtin_amdgcn_s_setprio(0);
        SCHED0(); BARRIER(); SCHED0();

        // ======== Phase 3: read a1(8) | stage B(t+1)h1 | MFMA M1N1 ========
        #pragma unroll
        for (int mi = 0; mi < 4; ++mi) {
            a1[mi][0] = *(const bf16x8*)(Aw + (4 + mi) * 2048 + rowb + sk0);
            a1[mi][1] = *(const bf16x8*)(Aw + (4 + mi) * 2048 + rowb + sk1);
        }
        STAGE(gB0, gB1, ldsB, tt + 1, 1);
        SCHED0(); BARRIER();
        LGKM0();
        __builtin_amdgcn_s_setprio(1);
        #pragma unroll
        for (int mi = 0; mi < 4; ++mi)
            #pragma unroll
            for (int nj = 0; nj < 2; ++nj) {
                acc[4 + mi][2 + nj] = __builtin_amdgcn_mfma_f32_16x16x32_bf16(a1[mi][0], b1[nj][0], acc[4 + mi][2 + nj], 0, 0, 0);
                acc[4 + mi][2 + nj] = __builtin_amdgcn_mfma_f32_16x16x32_bf16(a1[mi][1], b1[nj][1], acc[4 + mi][2 + nj], 0, 0, 0);
            }
        __builtin_amdgcn_s_setprio(0);
        SCHED0(); BARRIER(); SCHED0();

        // ======== Phase 4: stage A(t+2)h0 | vmcnt(2) | MFMA M1N0 ========
        STAGE(gA0, gA1, ldsA, tt + 2, 0);
        VMCNT(2);           // tile t+1 fully arrived; only A(t+2)h0 in flight
        SCHED0(); BARRIER();
        LGKM0();
        __builtin_amdgcn_s_setprio(1);
        #pragma unroll
        for (int mi = 0; mi < 4; ++mi)
            #pragma unroll
            for (int nj = 0; nj < 2; ++nj) {
                acc[4 + mi][nj] = __builtin_amdgcn_mfma_f32_16x16x32_bf16(a1[mi][0], b0[nj][0], acc[4 + mi][nj], 0, 0, 0);
                acc[4 + mi][nj] = __builtin_amdgcn_mfma_f32_16x16x32_bf16(a1[mi][1], b0[nj][1], acc[4 + mi][nj], 0, 0, 0);
            }
        __builtin_amdgcn_s_setprio(0);
        SCHED0(); BARRIER(); SCHED0();
    }

    VMCNT(0);   // drain tail dummy loads before LDS goes out of scope

    // ---- epilogue: out = xc + alpha * acc ----
    const float alpha = alpha_p[0];
    #pragma unroll
    for (int mi = 0; mi < 8; ++mi) {
        #pragma unroll
        for (int r = 0; r < 4; ++r) {
            const int m = m0 + wm + mi * 16 + l4 * 4 + r;
            #pragma unroll
            for (int nj = 0; nj < 4; ++nj) {
                const int n = n0 + wn + nj * 16 + l15;
                const size_t o = (size_t)m * HIDDEN + n;
                out[o] = xc[o] + alpha * acc[mi][nj][r];
            }
        }
    }
#undef STAGE
}

extern "C" void kernel_launch(void* const* d_in, const int* in_sizes, int n_in,
                              void* d_out, int out_size, void* d_ws, size_t ws_size,
                              hipStream_t stream) {
    const float* xc    = (const float*)d_in[0];
    const float* xp    = (const float*)d_in[1];
    const float* alpha = (const float*)d_in[2];
    const float* vals  = (const float*)d_in[3];
    const int*   idx   = (const int*)d_in[4];
    float* out = (float*)d_out;

    float*          W   = (float*)d_ws;                                   // 16 MB
    unsigned short* Wb  = (unsigned short*)((char*)d_ws + (16 << 20));    //  8 MB
    unsigned short* xpb = (unsigned short*)((char*)d_ws + (24 << 20));    // 32 MB

    const int nnz = in_sizes[3];
    const int M   = in_sizes[0] / HIDDEN;   // 8192

    (void)hipFuncSetAttribute((const void*)gemm_kernel,
                              hipFuncAttributeMaxDynamicSharedMemorySize, LDS_BYTES);

    hipMemsetAsync(W, 0, (size_t)HIDDEN * HIDDEN * sizeof(float), stream);
    build_w_kernel<<<(nnz + 255) / 256, 256, 0, stream>>>(vals, idx, idx + nnz, W, nnz);

    convert_kernel<<<2048, 256, 0, stream>>>(xp, xpb, in_sizes[1] / 8);
    convert_kernel<<<2048, 256, 0, stream>>>(W, Wb, (HIDDEN * HIDDEN) / 8);

    dim3 grid((M / 256) * 8);   // 32 m-tiles x 8 n-tiles = 256 blocks
    gemm_kernel<<<grid, 512, LDS_BYTES, stream>>>(xc, xpb, Wb, alpha, out);
}